// Round 12
// baseline (377.700 us; speedup 1.0000x reference)
//
#include <hip/hip_runtime.h>
#include <hip/hip_fp16.h>
#include <hip/hip_cooperative_groups.h>
#include <cstdint>

namespace cg = cooperative_groups;

// ---------------------------------------------------------------------------
// EpilepsyGNN: 3-layer GAT (4 heads x 32 -> 4x32 -> 1x32), BN(eval)+ReLU
// Build: ONE cooperative kernel (wcvt + bucket count/scan/emit/scatter with
// grid.sync between phases) — kills 5 launch gaps. Zero global atomics.
// GEMM: MFMA f16, LDS-staged A + W^T, f32 accum, al logits in epilogue.
// agg (frozen; R10/R11 showed it's fabric-pinned at ~41us): no-max softmax,
// exp hoisted to staging, edge-pair f16 gathers.
// ---------------------------------------------------------------------------

#define NBCHUNK 128   // edge chunks for bucket counting/emission
#define MAXBK 512     // max buckets of 128 nodes (N <= 65536; packing needs it)

typedef _Float16 f16x8 __attribute__((ext_vector_type(8)));
typedef float f32x4 __attribute__((ext_vector_type(4)));

__device__ __forceinline__ float lrelu02(float x) {
  return x > 0.f ? x : 0.2f * x;
}

__device__ __forceinline__ float expw(float x) {
  return __expf(fminf(x, 80.f));   // clamp is a no-op for this data; inf guard
}

// thread-0 sniff: int64 (little-endian) edge_index has all-odd words == 0
__device__ __forceinline__ int detect64(const unsigned* ei) {
  int is64 = 1;
  for (int i = 1; i < 128; i += 2)
    if (ei[i] != 0u) { is64 = 0; break; }
  return is64;
}

// --- ONE cooperative build kernel ------------------------------------------
// grid = max(nbk, NBCHUNK+1) blocks x 256. Phases separated by grid.sync():
//  1: blocks [0,NBCHUNK) edge-chunk histograms; blocks >= NBCHUNK: W->Wt f16
//  2: blocks [0,nbk) per-bucket chunk scan -> counts (exclusive), T totals
//  3: block 0 wave 0: exclusive scan T -> EB
//  4: blocks [0,NBCHUNK): emit packed (dloc<<16|src) bucket-contiguously
//  5: blocks [0,nbk): per-bucket hist -> row_ptr/self-loops/scatter csr_src
__global__ __launch_bounds__(256) void build_kernel(
    const void* __restrict__ ei, int E, int n, int nbk, int chunk,
    const float* __restrict__ W1, const float* __restrict__ W2,
    const float* __restrict__ W3,
    _Float16* __restrict__ Wt1, _Float16* __restrict__ Wt2,
    _Float16* __restrict__ Wt3,
    int* __restrict__ counts, int* __restrict__ T, int* __restrict__ EB,
    unsigned* __restrict__ binned, int* __restrict__ row_ptr,
    int* __restrict__ csr_src) {
  cg::grid_group grid = cg::this_grid();
  __shared__ int sH[MAXBK];
  __shared__ int sC[128];
  __shared__ int sMisc[2];   // [0]=wave carry, [1]=is64
  const int b = blockIdx.x;
  const int t = threadIdx.x;

  // ---- phase 1 ----
  if (b < NBCHUNK) {
    for (int i = t; i < nbk; i += 256) sH[i] = 0;
    if (t == 0) sMisc[1] = detect64((const unsigned*)ei);
    __syncthreads();
    int lo = b * chunk;
    int hi = lo + chunk; if (hi > E) hi = E;
    const bool is64 = sMisc[1] != 0;
    for (int e = lo + t; e < hi; e += 256) {
      int d = is64 ? (int)((const long long*)ei)[(size_t)E + e] : ((const int*)ei)[E + e];
      atomicAdd(&sH[d >> 7], 1);
    }
    __syncthreads();
    for (int i = t; i < nbk; i += 256)
      counts[(size_t)b * nbk + i] = sH[i];
  } else {
    // W -> Wt f16 transposes (36864 elements over the idle blocks)
    int nOther = gridDim.x - NBCHUNK;
    for (int idx = (b - NBCHUNK) * 256 + t; idx < 36864; idx += nOther * 256) {
      if (idx < 16384) {
        int k = idx >> 7, c = idx & 127;
        Wt1[(size_t)c * 128 + k] = (_Float16)W1[idx];
      } else if (idx < 32768) {
        int i = idx - 16384;
        int k = i >> 7, c = i & 127;
        Wt2[(size_t)c * 128 + k] = (_Float16)W2[i];
      } else {
        int i = idx - 32768;
        int k = i >> 5, c = i & 31;
        Wt3[(size_t)c * 128 + k] = (_Float16)W3[i];
      }
    }
  }
  grid.sync();

  // ---- phase 2: per-bucket exclusive scan over chunks (128 lanes used) ----
  if (b < nbk) {
    int lane = t & 63;
    int v = (t < 128) ? counts[(size_t)t * nbk + b] : 0;
    int inc = v;
#pragma unroll
    for (int off = 1; off < 64; off <<= 1) {
      int u = __shfl_up(inc, off);
      if (lane >= off) inc += u;
    }
    if (t == 63) sMisc[0] = inc;
    __syncthreads();
    int wb = (t >= 64 && t < 128) ? sMisc[0] : 0;
    if (t < 128) counts[(size_t)t * nbk + b] = wb + inc - v;
    if (t == 127) T[b] = wb + inc;
  }
  grid.sync();

  // ---- phase 3: single-wave exclusive scan of bucket totals -> EB ----
  if (b == 0 && t < 64) {
    int lane = t;
    int carry = 0;
    for (int start = 0; start < nbk; start += 64) {
      int i = start + lane;
      int v = (i < nbk) ? T[i] : 0;
      int inc = v;
#pragma unroll
      for (int off = 1; off < 64; off <<= 1) {
        int u = __shfl_up(inc, off);
        if (lane >= off) inc += u;
      }
      if (i < nbk) EB[i] = inc - v + carry;
      carry += __shfl(inc, 63);
    }
    if (lane == 0) EB[nbk] = carry;
  }
  grid.sync();

  // ---- phase 4: emit packed (dloc<<16 | src) ----
  if (b < NBCHUNK) {
    for (int i = t; i < nbk; i += 256)
      sH[i] = counts[(size_t)b * nbk + i] + EB[i];
    if (t == 0) sMisc[1] = detect64((const unsigned*)ei);
    __syncthreads();
    int lo = b * chunk;
    int hi = lo + chunk; if (hi > E) hi = E;
    const bool is64 = sMisc[1] != 0;
    for (int e = lo + t; e < hi; e += 256) {
      int s, d;
      if (is64) {
        const long long* p = (const long long*)ei;
        s = (int)p[e];
        d = (int)p[(size_t)E + e];
      } else {
        const int* p = (const int*)ei;
        s = p[e];
        d = p[E + e];
      }
      int pos = atomicAdd(&sH[d >> 7], 1);   // LDS atomic
      binned[pos] = ((unsigned)(d & 127) << 16) | (unsigned)s;
    }
  }
  grid.sync();

  // ---- phase 5: per-bucket histogram -> row_ptr + self-loops + scatter ----
  if (b < nbk) {
    const int bb = b << 7;
    if (t < 128) sH[t] = 0;
    __syncthreads();
    const int lo = EB[b], hi = EB[b + 1];
    for (int i = lo + t; i < hi; i += 256)
      atomicAdd(&sH[binned[i] >> 16], 1);
    __syncthreads();
    int lane = t & 63;
    int v = (t < 128) ? sH[t] : 0;
    int inc = v;
#pragma unroll
    for (int off = 1; off < 64; off <<= 1) {
      int u = __shfl_up(inc, off);
      if (lane >= off) inc += u;
    }
    if (t == 63) sMisc[0] = inc;
    __syncthreads();
    int exc = ((t >= 64 && t < 128) ? sMisc[0] : 0) + inc - v;
    if (t < 128 && bb + t < n) {
      int rp = EB[b] + bb + t + exc;
      row_ptr[bb + t] = rp;
      csr_src[rp] = bb + t;            // self loop at slot 0
      sC[t] = rp + 1;
    }
    if (b == 0 && t == 0) row_ptr[n] = E + n;
    __syncthreads();
    for (int i = lo + t; i < hi; i += 256) {
      unsigned pv = binned[i];
      int pos = atomicAdd(&sC[pv >> 16], 1);
      csr_src[pos] = (int)(pv & 0xFFFFu);
    }
  }
}

// --- MFMA GEMM + al epilogue: A[n,128]@W[128,OUTC] -> H(f16), alS/alD(f32) --
template <int OUTC, int H, typename AT>
__global__ __launch_bounds__(256) void mfma_gemm_al_kernel(
    const AT* __restrict__ A, const _Float16* __restrict__ Wt,
    const float* __restrict__ a_src, const float* __restrict__ a_dst,
    __half* __restrict__ Hout, float* __restrict__ alS, float* __restrict__ alD,
    int n) {
  constexpr int NT = OUTC / 16;    // col tiles per wave (8 or 2)
  constexpr int APH = 136;         // LDS row stride in halves (16B-aligned rows)

  __shared__ __align__(16) _Float16 A_lds[64 * APH];
  __shared__ __align__(16) _Float16 W_lds[OUTC * APH];

  const int t = threadIdx.x;
  const int r0 = blockIdx.x * 64;

  if constexpr (sizeof(AT) == 4) {
#pragma unroll
    for (int i = 0; i < 8; ++i) {
      int slot = t + i * 256;
      int r = slot >> 5, q = slot & 31;
      float4 v = make_float4(0.f, 0.f, 0.f, 0.f);
      if (r0 + r < n) v = *(const float4*)((const float*)A + (size_t)(r0 + r) * 128 + q * 4);
      __half2 p0 = __floats2half2_rn(v.x, v.y);
      __half2 p1 = __floats2half2_rn(v.z, v.w);
      uint2 pk;
      pk.x = *(unsigned*)&p0;
      pk.y = *(unsigned*)&p1;
      *(uint2*)&A_lds[r * APH + q * 4] = pk;
    }
  } else {
#pragma unroll
    for (int i = 0; i < 4; ++i) {
      int slot = t + i * 256;
      int r = slot >> 4, q = slot & 15;
      uint4 raw = make_uint4(0u, 0u, 0u, 0u);
      if (r0 + r < n) raw = *(const uint4*)((const __half*)A + (size_t)(r0 + r) * 128 + q * 8);
      *(uint4*)&A_lds[r * APH + q * 8] = raw;
    }
  }
#pragma unroll
  for (int i = 0; i < OUTC / 16; ++i) {
    int slot = t + i * 256;
    int c = slot >> 4, q = slot & 15;
    uint4 raw = *(const uint4*)(Wt + (size_t)c * 128 + q * 8);
    *(uint4*)&W_lds[c * APH + q * 8] = raw;
  }
  __syncthreads();

  const int w = t >> 6;
  const int lane = t & 63;
  const int lrow = lane & 15;
  const int lk = lane >> 4;

  f32x4 acc[NT];
#pragma unroll
  for (int i = 0; i < NT; ++i) acc[i] = (f32x4){0.f, 0.f, 0.f, 0.f};

#pragma unroll
  for (int kc = 0; kc < 4; ++kc) {
    f16x8 a = *(const f16x8*)&A_lds[(w * 16 + lrow) * APH + kc * 32 + lk * 8];
#pragma unroll
    for (int ct = 0; ct < NT; ++ct) {
      f16x8 b = *(const f16x8*)&W_lds[(ct * 16 + lrow) * APH + kc * 32 + lk * 8];
      acc[ct] = __builtin_amdgcn_mfma_f32_16x16x32_f16(a, b, acc[ct], 0, 0, 0);
    }
  }

  const int rbase = r0 + w * 16 + lk * 4;
#pragma unroll
  for (int ct = 0; ct < NT; ++ct) {
#pragma unroll
    for (int j = 0; j < 4; ++j) {
      int r = rbase + j;
      if (r < n) Hout[(size_t)r * OUTC + ct * 16 + lrow] = __float2half(acc[ct][j]);
    }
  }

#pragma unroll
  for (int h = 0; h < H; ++h) {
    float as0 = a_src[h * 32 + lrow], as1 = a_src[h * 32 + 16 + lrow];
    float ad0 = a_dst[h * 32 + lrow], ad1 = a_dst[h * 32 + 16 + lrow];
#pragma unroll
    for (int j = 0; j < 4; ++j) {
      float ps = acc[2 * h][j] * as0 + acc[2 * h + 1][j] * as1;
      float pd = acc[2 * h][j] * ad0 + acc[2 * h + 1][j] * ad1;
#pragma unroll
      for (int off = 1; off < 16; off <<= 1) {
        ps += __shfl_xor(ps, off);
        pd += __shfl_xor(pd, off);
      }
      if (lrow == 0) {
        int r = rbase + j;
        if (r < n) {
          alS[(size_t)r * H + h] = ps;
          alD[(size_t)r * H + h] = pd;
        }
      }
    }
  }
}

// --- agg: staged exp weights, edge-PAIR f16 gathers, shfl combine -----------
template <int H, bool BN, typename OutT>
__global__ __launch_bounds__(256) void agg_kernel(
    const int* __restrict__ row_ptr, const int* __restrict__ csr_src,
    const float* __restrict__ alS, const float* __restrict__ alD,
    const __half* __restrict__ hfeat, const float* __restrict__ bias,
    const float* __restrict__ bnw, const float* __restrict__ bnb,
    const float* __restrict__ bnm, const float* __restrict__ bnv,
    OutT* __restrict__ out, int n) {
  constexpr int LPN = (H == 4) ? 64 : 32;     // lanes per node
  constexpr int NPB = 256 / LPN;              // node slots per block
  constexpr int KCAP = 96;                    // staged-edge capacity
  constexpr int RSH = (H == 4) ? 8 : 6;       // log2(row bytes): 256B / 64B

  __shared__ __align__(16) float sW[NPB][KCAP * H];
  __shared__ int sOff[NPB][KCAP];

  const int slot = threadIdx.x / LPN;
  const int sl = threadIdx.x % LPN;
  const int v = blockIdx.x * NPB + slot;
  const bool active = v < n;
  const char* hb = (const char*)hfeat;

  int rs = 0, re = 0;
  if (active) { rs = row_ptr[v]; re = row_ptr[v + 1]; }
  const int deg = re - rs;
  const int degS = deg < KCAP ? deg : KCAP;

  if constexpr (H == 4) {
    float4 ad4 = make_float4(0.f, 0.f, 0.f, 0.f);
    if (active) ad4 = *(const float4*)(alD + (size_t)v * 4);
    float den0 = 0.f, den1 = 0.f, den2 = 0.f, den3 = 0.f;
    for (int k = sl; k < degS; k += 64) {
      int s = csr_src[rs + k];
      sOff[slot][k] = s << RSH;
      float4 a4 = *(const float4*)(alS + (size_t)s * 4);
      float u0 = expw(lrelu02(a4.x + ad4.x));
      float u1 = expw(lrelu02(a4.y + ad4.y));
      float u2 = expw(lrelu02(a4.z + ad4.z));
      float u3 = expw(lrelu02(a4.w + ad4.w));
      ((float4*)&sW[slot][0])[k] = make_float4(u0, u1, u2, u3);
      den0 += u0; den1 += u1; den2 += u2; den3 += u3;
    }
#pragma unroll
    for (int off = 32; off >= 1; off >>= 1) {
      den0 += __shfl_xor(den0, off);
      den1 += __shfl_xor(den1, off);
      den2 += __shfl_xor(den2, off);
      den3 += __shfl_xor(den3, off);
    }

    // edge-pair: lanes 0-31 even edges, lanes 32-63 odd edges; 4 ch/lane
    const int half = sl >> 5;
    const int l5 = sl & 31;
    const int c = l5 * 4;
    const int h = l5 >> 3;
    const unsigned cb2 = (unsigned)(c * 2);
    float a0 = 0.f, a1 = 0.f, a2 = 0.f, a3 = 0.f;
    int j = 0;
    for (; j + 8 <= degS; j += 8) {
      int e0 = j + half, e1 = j + 2 + half, e2 = j + 4 + half, e3 = j + 6 + half;
      unsigned o0 = (unsigned)sOff[slot][e0] + cb2;
      unsigned o1 = (unsigned)sOff[slot][e1] + cb2;
      unsigned o2 = (unsigned)sOff[slot][e2] + cb2;
      unsigned o3 = (unsigned)sOff[slot][e3] + cb2;
      float w0 = sW[slot][e0 * 4 + h], w1 = sW[slot][e1 * 4 + h];
      float w2 = sW[slot][e2 * 4 + h], w3 = sW[slot][e3 * 4 + h];
      uint2 r0v = *(const uint2*)(hb + o0);
      uint2 r1v = *(const uint2*)(hb + o1);
      uint2 r2v = *(const uint2*)(hb + o2);
      uint2 r3v = *(const uint2*)(hb + o3);
      float2 f0l = __half22float2(*(const __half2*)&r0v.x);
      float2 f0h = __half22float2(*(const __half2*)&r0v.y);
      float2 f1l = __half22float2(*(const __half2*)&r1v.x);
      float2 f1h = __half22float2(*(const __half2*)&r1v.y);
      float2 f2l = __half22float2(*(const __half2*)&r2v.x);
      float2 f2h = __half22float2(*(const __half2*)&r2v.y);
      float2 f3l = __half22float2(*(const __half2*)&r3v.x);
      float2 f3h = __half22float2(*(const __half2*)&r3v.y);
      a0 = fmaf(w0, f0l.x, a0); a1 = fmaf(w0, f0l.y, a1);
      a2 = fmaf(w0, f0h.x, a2); a3 = fmaf(w0, f0h.y, a3);
      a0 = fmaf(w1, f1l.x, a0); a1 = fmaf(w1, f1l.y, a1);
      a2 = fmaf(w1, f1h.x, a2); a3 = fmaf(w1, f1h.y, a3);
      a0 = fmaf(w2, f2l.x, a0); a1 = fmaf(w2, f2l.y, a1);
      a2 = fmaf(w2, f2h.x, a2); a3 = fmaf(w2, f2h.y, a3);
      a0 = fmaf(w3, f3l.x, a0); a1 = fmaf(w3, f3l.y, a1);
      a2 = fmaf(w3, f3h.x, a2); a3 = fmaf(w3, f3h.y, a3);
    }
    for (; j + 2 <= degS; j += 2) {
      int e = j + half;
      unsigned o = (unsigned)sOff[slot][e] + cb2;
      float w = sW[slot][e * 4 + h];
      uint2 rv = *(const uint2*)(hb + o);
      float2 fl = __half22float2(*(const __half2*)&rv.x);
      float2 fh = __half22float2(*(const __half2*)&rv.y);
      a0 = fmaf(w, fl.x, a0); a1 = fmaf(w, fl.y, a1);
      a2 = fmaf(w, fh.x, a2); a3 = fmaf(w, fh.y, a3);
    }
    if ((degS & 1) && half == 0) {
      int e = degS - 1;
      unsigned o = (unsigned)sOff[slot][e] + cb2;
      float w = sW[slot][e * 4 + h];
      uint2 rv = *(const uint2*)(hb + o);
      float2 fl = __half22float2(*(const __half2*)&rv.x);
      float2 fh = __half22float2(*(const __half2*)&rv.y);
      a0 = fmaf(w, fl.x, a0); a1 = fmaf(w, fl.y, a1);
      a2 = fmaf(w, fh.x, a2); a3 = fmaf(w, fh.y, a3);
    }
    a0 += __shfl_xor(a0, 32);
    a1 += __shfl_xor(a1, 32);
    a2 += __shfl_xor(a2, 32);
    a3 += __shfl_xor(a3, 32);

    float den = (h == 0) ? den0 : (h == 1) ? den1 : (h == 2) ? den2 : den3;
    if (deg > KCAP) {  // cold fallback (serial, never triggers at deg~17)
      float adh = alD[(size_t)v * 4 + h];
      if (half == 0) {
        for (int e = rs + KCAP; e < re; ++e) {
          int s = csr_src[e];
          float u = expw(lrelu02(alS[(size_t)s * 4 + h] + adh));
          den += u;
          uint2 rv = *(const uint2*)(hb + ((unsigned)(s << RSH) + cb2));
          float2 fl = __half22float2(*(const __half2*)&rv.x);
          float2 fh = __half22float2(*(const __half2*)&rv.y);
          a0 = fmaf(u, fl.x, a0); a1 = fmaf(u, fl.y, a1);
          a2 = fmaf(u, fh.x, a2); a3 = fmaf(u, fh.y, a3);
        }
      } else {
        for (int e = rs + KCAP; e < re; ++e) {
          int s = csr_src[e];
          den += expw(lrelu02(alS[(size_t)s * 4 + h] + adh));
        }
      }
    }
    if (active && half == 0) {
      float inv = 1.f / (den + 1e-16f);
      float4 b4 = *(const float4*)(bias + c);
      float g0 = a0 * inv + b4.x;
      float g1 = a1 * inv + b4.y;
      float g2 = a2 * inv + b4.z;
      float g3 = a3 * inv + b4.w;
      if constexpr (BN) {
        float4 bw = *(const float4*)(bnw + c);
        float4 bb = *(const float4*)(bnb + c);
        float4 bm = *(const float4*)(bnm + c);
        float4 bv = *(const float4*)(bnv + c);
        g0 = fmaxf((g0 - bm.x) * (bw.x * rsqrtf(bv.x + 1e-5f)) + bb.x, 0.f);
        g1 = fmaxf((g1 - bm.y) * (bw.y * rsqrtf(bv.y + 1e-5f)) + bb.y, 0.f);
        g2 = fmaxf((g2 - bm.z) * (bw.z * rsqrtf(bv.z + 1e-5f)) + bb.z, 0.f);
        g3 = fmaxf((g3 - bm.w) * (bw.w * rsqrtf(bv.w + 1e-5f)) + bb.w, 0.f);
      }
      if constexpr (sizeof(OutT) == 2) {
        __half2 p0 = __floats2half2_rn(g0, g1);
        __half2 p1 = __floats2half2_rn(g2, g3);
        uint2 pk;
        pk.x = *(unsigned*)&p0;
        pk.y = *(unsigned*)&p1;
        *(uint2*)((__half*)out + (size_t)v * 128 + c) = pk;
      } else {
        *(float4*)((float*)out + (size_t)v * 128 + c) = make_float4(g0, g1, g2, g3);
      }
    }
  } else {  // H == 1, C == 32
    float ad = active ? alD[v] : 0.f;
    float den = 0.f;
    for (int k = sl; k < degS; k += 32) {
      int s = csr_src[rs + k];
      sOff[slot][k] = s << RSH;
      float u = expw(lrelu02(alS[s] + ad));
      sW[slot][k] = u;
      den += u;
    }
#pragma unroll
    for (int off = 16; off >= 1; off >>= 1) den += __shfl_xor(den, off);

    // edge-pair: lanes 0-15 even edges, 16-31 odd; 2 ch/lane (__half2)
    const int quad = sl >> 4;
    const int l4 = sl & 15;
    const int c2 = l4 * 2;
    const unsigned cb2 = (unsigned)(c2 * 2);
    float a0 = 0.f, a1 = 0.f;
    int j = 0;
    for (; j + 4 <= degS; j += 4) {
      int e0 = j + quad, e1 = j + 2 + quad;
      unsigned o0 = (unsigned)sOff[slot][e0] + cb2;
      unsigned o1 = (unsigned)sOff[slot][e1] + cb2;
      float w0 = sW[slot][e0], w1 = sW[slot][e1];
      float2 f0 = __half22float2(*(const __half2*)(hb + o0));
      float2 f1 = __half22float2(*(const __half2*)(hb + o1));
      a0 = fmaf(w0, f0.x, a0); a1 = fmaf(w0, f0.y, a1);
      a0 = fmaf(w1, f1.x, a0); a1 = fmaf(w1, f1.y, a1);
    }
    for (; j + 2 <= degS; j += 2) {
      int e = j + quad;
      unsigned o = (unsigned)sOff[slot][e] + cb2;
      float w = sW[slot][e];
      float2 f = __half22float2(*(const __half2*)(hb + o));
      a0 = fmaf(w, f.x, a0); a1 = fmaf(w, f.y, a1);
    }
    if ((degS & 1) && quad == 0) {
      int e = degS - 1;
      unsigned o = (unsigned)sOff[slot][e] + cb2;
      float w = sW[slot][e];
      float2 f = __half22float2(*(const __half2*)(hb + o));
      a0 = fmaf(w, f.x, a0); a1 = fmaf(w, f.y, a1);
    }
    a0 += __shfl_xor(a0, 16);
    a1 += __shfl_xor(a1, 16);

    if (deg > KCAP) {
      if (quad == 0) {
        for (int e = rs + KCAP; e < re; ++e) {
          int s = csr_src[e];
          float u = expw(lrelu02(alS[s] + ad));
          den += u;
          float2 f = __half22float2(*(const __half2*)(hb + ((unsigned)(s << RSH) + cb2)));
          a0 = fmaf(u, f.x, a0); a1 = fmaf(u, f.y, a1);
        }
      } else {
        for (int e = rs + KCAP; e < re; ++e)
          den += expw(lrelu02(alS[csr_src[e]] + ad));
      }
    }
    if (active && quad == 0) {
      float inv = 1.f / (den + 1e-16f);
      float2 b2v = *(const float2*)(bias + c2);
      ((float2*)((float*)out + (size_t)v * 32))[l4] =
          make_float2(a0 * inv + b2v.x, a1 * inv + b2v.y);
    }
  }
}

// ---------------------------------------------------------------------------
extern "C" void kernel_launch(void* const* d_in, const int* in_sizes, int n_in,
                              void* d_out, int out_size, void* d_ws, size_t ws_size,
                              hipStream_t stream) {
  const float* x = (const float*)d_in[0];
  const void* ei = d_in[1];
  const float* w1 = (const float*)d_in[2];
  const float* as1 = (const float*)d_in[3];
  const float* ad1 = (const float*)d_in[4];
  const float* b1 = (const float*)d_in[5];
  const float* bn1w = (const float*)d_in[6];
  const float* bn1b = (const float*)d_in[7];
  const float* bn1m = (const float*)d_in[8];
  const float* bn1v = (const float*)d_in[9];
  const float* w2 = (const float*)d_in[10];
  const float* as2 = (const float*)d_in[11];
  const float* ad2 = (const float*)d_in[12];
  const float* b2 = (const float*)d_in[13];
  const float* bn2w = (const float*)d_in[14];
  const float* bn2b = (const float*)d_in[15];
  const float* bn2m = (const float*)d_in[16];
  const float* bn2v = (const float*)d_in[17];
  const float* w3 = (const float*)d_in[18];
  const float* as3 = (const float*)d_in[19];
  const float* ad3 = (const float*)d_in[20];
  const float* b3 = (const float*)d_in[21];

  const int N = in_sizes[0] / 128;
  const int E = in_sizes[1] / 2;
  int nbk = (N + 127) / 128;
  const int chunk = (E + NBCHUNK - 1) / NBCHUNK;
  int buildGrid = nbk > (NBCHUNK + 64) ? nbk : (NBCHUNK + 64);

  // workspace layout (256B aligned slices)
  char* base = (char*)d_ws;
  size_t off = 0;
  auto alloc = [&](size_t bytes) {
    void* p = base + off;
    off = (off + bytes + 255) & ~(size_t)255;
    return p;
  };
  int* counts = (int*)alloc((size_t)NBCHUNK * nbk * 4);
  int* T = (int*)alloc((size_t)nbk * 4);
  int* EB = (int*)alloc((size_t)(nbk + 1) * 4);
  unsigned* binned = (unsigned*)alloc((size_t)E * 4);
  int* row_ptr = (int*)alloc((size_t)(N + 1) * 4);
  int* csr_src = (int*)alloc((size_t)(E + N) * 4);
  _Float16* Wt1 = (_Float16*)alloc((size_t)128 * 128 * 2);
  _Float16* Wt2 = (_Float16*)alloc((size_t)128 * 128 * 2);
  _Float16* Wt3 = (_Float16*)alloc((size_t)32 * 128 * 2);
  __half* hbuf = (__half*)alloc((size_t)N * 128 * 2);
  __half* gbuf = (__half*)alloc((size_t)N * 128 * 2);
  float* alS = (float*)alloc((size_t)N * 4 * 4);
  float* alD = (float*)alloc((size_t)N * 4 * 4);
  (void)ws_size;

  // ---- one cooperative build launch (wcvt + CSR, zero global atomics) ----
  {
    const void* ei_ = ei;
    int E_ = E, n_ = N, nbk_ = nbk, chunk_ = chunk;
    const float *W1_ = w1, *W2_ = w2, *W3_ = w3;
    _Float16 *Wt1_ = Wt1, *Wt2_ = Wt2, *Wt3_ = Wt3;
    int *counts_ = counts, *T_ = T, *EB_ = EB;
    unsigned* binned_ = binned;
    int *row_ptr_ = row_ptr, *csr_src_ = csr_src;
    void* args[] = {&ei_, &E_, &n_, &nbk_, &chunk_, &W1_, &W2_, &W3_,
                    &Wt1_, &Wt2_, &Wt3_, &counts_, &T_, &EB_, &binned_,
                    &row_ptr_, &csr_src_};
    hipLaunchCooperativeKernel((void*)build_kernel, dim3(buildGrid), dim3(256),
                               args, 0, stream);
  }

  const int rowBlocks = (N + 63) / 64;

  // ---- layer 1 ----
  mfma_gemm_al_kernel<128, 4, float><<<rowBlocks, 256, 0, stream>>>(
      x, Wt1, as1, ad1, hbuf, alS, alD, N);
  agg_kernel<4, true, __half><<<(N + 3) / 4, 256, 0, stream>>>(
      row_ptr, csr_src, alS, alD, hbuf, b1, bn1w, bn1b, bn1m, bn1v, gbuf, N);
  // ---- layer 2 ----
  mfma_gemm_al_kernel<128, 4, __half><<<rowBlocks, 256, 0, stream>>>(
      gbuf, Wt2, as2, ad2, hbuf, alS, alD, N);
  agg_kernel<4, true, __half><<<(N + 3) / 4, 256, 0, stream>>>(
      row_ptr, csr_src, alS, alD, hbuf, b2, bn2w, bn2b, bn2m, bn2v, gbuf, N);
  // ---- layer 3 ----
  mfma_gemm_al_kernel<32, 1, __half><<<rowBlocks, 256, 0, stream>>>(
      gbuf, Wt3, as3, ad3, hbuf, alS, alD, N);
  agg_kernel<1, false, float><<<(N + 7) / 8, 256, 0, stream>>>(
      row_ptr, csr_src, alS, alD, hbuf, b3, nullptr, nullptr, nullptr, nullptr,
      (float*)d_out, N);
}

// Round 13
// 209.569 us; speedup vs baseline: 1.8023x; 1.8023x over previous
//
#include <hip/hip_runtime.h>
#include <hip/hip_fp16.h>
#include <cstdint>

// ---------------------------------------------------------------------------
// EpilepsyGNN: 3-layer GAT (4 heads x 32 -> 4x32 -> 1x32), BN(eval)+ReLU
// R12 lesson: grid.sync costs ~50us/sync on 8-XCD MI355X -> cooperative build
// reverted. Build = 4 launches: bcount(+wcvt in spare blocks), bscanT(+EB
// scan in last block via decoupled ticket), bemit, bscatter2. Zero global
// atomics on hot paths. GEMM: MFMA f16. agg: fabric-pinned (R10/R11 nulls),
// no-max softmax, exp hoisted, edge-pair f16 gathers.
// ---------------------------------------------------------------------------

#define NBCHUNK 128   // edge chunks for bucket counting/emission
#define MAXBK 512     // max buckets of 128 nodes (N <= 65536; packing needs it)

typedef _Float16 f16x8 __attribute__((ext_vector_type(8)));
typedef float f32x4 __attribute__((ext_vector_type(4)));

__device__ __forceinline__ float lrelu02(float x) {
  return x > 0.f ? x : 0.2f * x;
}

__device__ __forceinline__ float expw(float x) {
  return __expf(fminf(x, 80.f));   // clamp is a no-op for this data; inf guard
}

// thread-0 sniff: int64 (little-endian) edge_index has all-odd words == 0
__device__ __forceinline__ int detect64(const unsigned* ei) {
  int is64 = 1;
  for (int i = 1; i < 128; i += 2)
    if (ei[i] != 0u) { is64 = 0; break; }
  return is64;
}

// --- phase 1: per-chunk LDS histogram; spare blocks do W->Wt f16 ------------
__global__ __launch_bounds__(256) void bcount_kernel(
    const void* __restrict__ ei, int E, int* __restrict__ counts,
    int nbk, int chunk,
    const float* __restrict__ W1, const float* __restrict__ W2,
    const float* __restrict__ W3,
    _Float16* __restrict__ Wt1, _Float16* __restrict__ Wt2,
    _Float16* __restrict__ Wt3, int* __restrict__ cnt) {
  const int b = blockIdx.x;
  const int t = threadIdx.x;
  if (b == 0 && t == 0) *cnt = 0;   // reset ticket for bscanT (stream-ordered)
  if (b < NBCHUNK) {
    __shared__ int hist[MAXBK];
    __shared__ int sIs64;
    for (int i = t; i < nbk; i += 256) hist[i] = 0;
    if (t == 0) sIs64 = detect64((const unsigned*)ei);
    __syncthreads();
    int lo = b * chunk;
    int hi = lo + chunk; if (hi > E) hi = E;
    const bool is64 = sIs64 != 0;
    for (int e = lo + t; e < hi; e += 256) {
      int d = is64 ? (int)((const long long*)ei)[(size_t)E + e] : ((const int*)ei)[E + e];
      atomicAdd(&hist[d >> 7], 1);
    }
    __syncthreads();
    for (int i = t; i < nbk; i += 256)
      counts[(size_t)b * nbk + i] = hist[i];
  } else {
    // W -> Wt f16 transposes over the 16 spare blocks
    for (int idx = (b - NBCHUNK) * 256 + t; idx < 36864; idx += 16 * 256) {
      if (idx < 16384) {
        int k = idx >> 7, c = idx & 127;
        Wt1[(size_t)c * 128 + k] = (_Float16)W1[idx];
      } else if (idx < 32768) {
        int i = idx - 16384;
        int k = i >> 7, c = i & 127;
        Wt2[(size_t)c * 128 + k] = (_Float16)W2[i];
      } else {
        int i = idx - 32768;
        int k = i >> 5, c = i & 31;
        Wt3[(size_t)c * 128 + k] = (_Float16)W3[i];
      }
    }
  }
}

// --- phase 2: per-bucket chunk scan; LAST block also scans T -> EB ----------
__global__ void bscanT_kernel(int* __restrict__ counts, int* __restrict__ T,
                              int* __restrict__ EB, int* __restrict__ cnt,
                              int nbk) {
  int b = blockIdx.x;
  int t = threadIdx.x;           // 128 threads
  int lane = t & 63;
  int v = counts[(size_t)t * nbk + b];
  int inc = v;
#pragma unroll
  for (int off = 1; off < 64; off <<= 1) {
    int u = __shfl_up(inc, off);
    if (lane >= off) inc += u;
  }
  __shared__ int w0;
  __shared__ int isLast;
  if (t == 63) w0 = inc;
  __syncthreads();
  int wb = (t >= 64) ? w0 : 0;
  counts[(size_t)t * nbk + b] = wb + inc - v;   // chunk-exclusive, bucket-local
  if (t == 127) T[b] = wb + inc;                // bucket edge total
  __threadfence();
  __syncthreads();
  if (t == 0) isLast = (atomicAdd(cnt, 1) == nbk - 1) ? 1 : 0;
  __syncthreads();
  if (isLast && t < 64) {        // decoupled final scan: T -> EB
    int carry = 0;
    for (int start = 0; start < nbk; start += 64) {
      int i = start + lane;
      int tv = (i < nbk) ? T[i] : 0;
      int ic = tv;
#pragma unroll
      for (int off = 1; off < 64; off <<= 1) {
        int u = __shfl_up(ic, off);
        if (lane >= off) ic += u;
      }
      if (i < nbk) EB[i] = ic - tv + carry;
      carry += __shfl(ic, 63);
    }
    if (lane == 0) EB[nbk] = carry;
  }
}

// --- phase 3: emit packed (dloc<<16 | src) bucket-contiguously --------------
__global__ __launch_bounds__(256) void bemit_kernel(const void* __restrict__ ei, int E,
                                                    const int* __restrict__ counts,
                                                    const int* __restrict__ EB,
                                                    int nbk, int chunk,
                                                    unsigned* __restrict__ binned) {
  __shared__ int cur[MAXBK];
  __shared__ int sIs64;
  for (int i = threadIdx.x; i < nbk; i += 256)
    cur[i] = counts[(size_t)blockIdx.x * nbk + i] + EB[i];
  if (threadIdx.x == 0) sIs64 = detect64((const unsigned*)ei);
  __syncthreads();
  int lo = blockIdx.x * chunk;
  int hi = lo + chunk; if (hi > E) hi = E;
  const bool is64 = sIs64 != 0;
  for (int e = lo + threadIdx.x; e < hi; e += 256) {
    int s, d;
    if (is64) {
      const long long* p = (const long long*)ei;
      s = (int)p[e];
      d = (int)p[(size_t)E + e];
    } else {
      const int* p = (const int*)ei;
      s = p[e];
      d = p[E + e];
    }
    int pos = atomicAdd(&cur[d >> 7], 1);   // LDS atomic: cheap
    binned[pos] = ((unsigned)(d & 127) << 16) | (unsigned)s;   // N <= 65536
  }
}

// --- phase 4: per-bucket histogram -> row_ptr + self-loops + scatter --------
__global__ __launch_bounds__(256) void bscatter2_kernel(const unsigned* __restrict__ binned,
                                                        const int* __restrict__ EB,
                                                        int* __restrict__ row_ptr,
                                                        int* __restrict__ csr_src,
                                                        int n, int E) {
  __shared__ int hist[128];
  __shared__ int cur[128];
  __shared__ int w0s;
  const int b = blockIdx.x;
  const int t = threadIdx.x;
  const int bb = b << 7;
  if (t < 128) hist[t] = 0;
  __syncthreads();
  const int lo = EB[b], hi = EB[b + 1];
  for (int i = lo + t; i < hi; i += 256)
    atomicAdd(&hist[binned[i] >> 16], 1);
  __syncthreads();
  int lane = t & 63;
  int v = (t < 128) ? hist[t] : 0;
  int inc = v;
#pragma unroll
  for (int off = 1; off < 64; off <<= 1) {
    int u = __shfl_up(inc, off);
    if (lane >= off) inc += u;
  }
  if (t == 63) w0s = inc;
  __syncthreads();
  int exc = ((t >= 64 && t < 128) ? w0s : 0) + inc - v;
  if (t < 128 && bb + t < n) {
    int rp = EB[b] + bb + t + exc;   // edges-before-node + self-loops-before
    row_ptr[bb + t] = rp;
    csr_src[rp] = bb + t;            // self loop at slot 0
    cur[t] = rp + 1;
  }
  if (b == 0 && t == 0) row_ptr[n] = E + n;
  __syncthreads();
  for (int i = lo + t; i < hi; i += 256) {
    unsigned pv = binned[i];
    int pos = atomicAdd(&cur[pv >> 16], 1);
    csr_src[pos] = (int)(pv & 0xFFFFu);
  }
}

// --- MFMA GEMM + al epilogue: A[n,128]@W[128,OUTC] -> H(f16), alS/alD(f32) --
template <int OUTC, int H, typename AT>
__global__ __launch_bounds__(256) void mfma_gemm_al_kernel(
    const AT* __restrict__ A, const _Float16* __restrict__ Wt,
    const float* __restrict__ a_src, const float* __restrict__ a_dst,
    __half* __restrict__ Hout, float* __restrict__ alS, float* __restrict__ alD,
    int n) {
  constexpr int NT = OUTC / 16;    // col tiles per wave (8 or 2)
  constexpr int APH = 136;         // LDS row stride in halves (16B-aligned rows)

  __shared__ __align__(16) _Float16 A_lds[64 * APH];
  __shared__ __align__(16) _Float16 W_lds[OUTC * APH];

  const int t = threadIdx.x;
  const int r0 = blockIdx.x * 64;

  if constexpr (sizeof(AT) == 4) {
#pragma unroll
    for (int i = 0; i < 8; ++i) {
      int slot = t + i * 256;
      int r = slot >> 5, q = slot & 31;
      float4 v = make_float4(0.f, 0.f, 0.f, 0.f);
      if (r0 + r < n) v = *(const float4*)((const float*)A + (size_t)(r0 + r) * 128 + q * 4);
      __half2 p0 = __floats2half2_rn(v.x, v.y);
      __half2 p1 = __floats2half2_rn(v.z, v.w);
      uint2 pk;
      pk.x = *(unsigned*)&p0;
      pk.y = *(unsigned*)&p1;
      *(uint2*)&A_lds[r * APH + q * 4] = pk;
    }
  } else {
#pragma unroll
    for (int i = 0; i < 4; ++i) {
      int slot = t + i * 256;
      int r = slot >> 4, q = slot & 15;
      uint4 raw = make_uint4(0u, 0u, 0u, 0u);
      if (r0 + r < n) raw = *(const uint4*)((const __half*)A + (size_t)(r0 + r) * 128 + q * 8);
      *(uint4*)&A_lds[r * APH + q * 8] = raw;
    }
  }
#pragma unroll
  for (int i = 0; i < OUTC / 16; ++i) {
    int slot = t + i * 256;
    int c = slot >> 4, q = slot & 15;
    uint4 raw = *(const uint4*)(Wt + (size_t)c * 128 + q * 8);
    *(uint4*)&W_lds[c * APH + q * 8] = raw;
  }
  __syncthreads();

  const int w = t >> 6;
  const int lane = t & 63;
  const int lrow = lane & 15;
  const int lk = lane >> 4;

  f32x4 acc[NT];
#pragma unroll
  for (int i = 0; i < NT; ++i) acc[i] = (f32x4){0.f, 0.f, 0.f, 0.f};

#pragma unroll
  for (int kc = 0; kc < 4; ++kc) {
    f16x8 a = *(const f16x8*)&A_lds[(w * 16 + lrow) * APH + kc * 32 + lk * 8];
#pragma unroll
    for (int ct = 0; ct < NT; ++ct) {
      f16x8 b = *(const f16x8*)&W_lds[(ct * 16 + lrow) * APH + kc * 32 + lk * 8];
      acc[ct] = __builtin_amdgcn_mfma_f32_16x16x32_f16(a, b, acc[ct], 0, 0, 0);
    }
  }

  const int rbase = r0 + w * 16 + lk * 4;
#pragma unroll
  for (int ct = 0; ct < NT; ++ct) {
#pragma unroll
    for (int j = 0; j < 4; ++j) {
      int r = rbase + j;
      if (r < n) Hout[(size_t)r * OUTC + ct * 16 + lrow] = __float2half(acc[ct][j]);
    }
  }

#pragma unroll
  for (int h = 0; h < H; ++h) {
    float as0 = a_src[h * 32 + lrow], as1 = a_src[h * 32 + 16 + lrow];
    float ad0 = a_dst[h * 32 + lrow], ad1 = a_dst[h * 32 + 16 + lrow];
#pragma unroll
    for (int j = 0; j < 4; ++j) {
      float ps = acc[2 * h][j] * as0 + acc[2 * h + 1][j] * as1;
      float pd = acc[2 * h][j] * ad0 + acc[2 * h + 1][j] * ad1;
#pragma unroll
      for (int off = 1; off < 16; off <<= 1) {
        ps += __shfl_xor(ps, off);
        pd += __shfl_xor(pd, off);
      }
      if (lrow == 0) {
        int r = rbase + j;
        if (r < n) {
          alS[(size_t)r * H + h] = ps;
          alD[(size_t)r * H + h] = pd;
        }
      }
    }
  }
}

// --- agg: staged exp weights, edge-PAIR f16 gathers, shfl combine -----------
template <int H, bool BN, typename OutT>
__global__ __launch_bounds__(256) void agg_kernel(
    const int* __restrict__ row_ptr, const int* __restrict__ csr_src,
    const float* __restrict__ alS, const float* __restrict__ alD,
    const __half* __restrict__ hfeat, const float* __restrict__ bias,
    const float* __restrict__ bnw, const float* __restrict__ bnb,
    const float* __restrict__ bnm, const float* __restrict__ bnv,
    OutT* __restrict__ out, int n) {
  constexpr int LPN = (H == 4) ? 64 : 32;     // lanes per node
  constexpr int NPB = 256 / LPN;              // node slots per block
  constexpr int KCAP = 96;                    // staged-edge capacity
  constexpr int RSH = (H == 4) ? 8 : 6;       // log2(row bytes): 256B / 64B

  __shared__ __align__(16) float sW[NPB][KCAP * H];
  __shared__ int sOff[NPB][KCAP];

  const int slot = threadIdx.x / LPN;
  const int sl = threadIdx.x % LPN;
  const int v = blockIdx.x * NPB + slot;
  const bool active = v < n;
  const char* hb = (const char*)hfeat;

  int rs = 0, re = 0;
  if (active) { rs = row_ptr[v]; re = row_ptr[v + 1]; }
  const int deg = re - rs;
  const int degS = deg < KCAP ? deg : KCAP;

  if constexpr (H == 4) {
    float4 ad4 = make_float4(0.f, 0.f, 0.f, 0.f);
    if (active) ad4 = *(const float4*)(alD + (size_t)v * 4);
    float den0 = 0.f, den1 = 0.f, den2 = 0.f, den3 = 0.f;
    for (int k = sl; k < degS; k += 64) {
      int s = csr_src[rs + k];
      sOff[slot][k] = s << RSH;
      float4 a4 = *(const float4*)(alS + (size_t)s * 4);
      float u0 = expw(lrelu02(a4.x + ad4.x));
      float u1 = expw(lrelu02(a4.y + ad4.y));
      float u2 = expw(lrelu02(a4.z + ad4.z));
      float u3 = expw(lrelu02(a4.w + ad4.w));
      ((float4*)&sW[slot][0])[k] = make_float4(u0, u1, u2, u3);
      den0 += u0; den1 += u1; den2 += u2; den3 += u3;
    }
#pragma unroll
    for (int off = 32; off >= 1; off >>= 1) {
      den0 += __shfl_xor(den0, off);
      den1 += __shfl_xor(den1, off);
      den2 += __shfl_xor(den2, off);
      den3 += __shfl_xor(den3, off);
    }

    // edge-pair: lanes 0-31 even edges, lanes 32-63 odd edges; 4 ch/lane
    const int half = sl >> 5;
    const int l5 = sl & 31;
    const int c = l5 * 4;
    const int h = l5 >> 3;
    const unsigned cb2 = (unsigned)(c * 2);
    float a0 = 0.f, a1 = 0.f, a2 = 0.f, a3 = 0.f;
    int j = 0;
    for (; j + 8 <= degS; j += 8) {
      int e0 = j + half, e1 = j + 2 + half, e2 = j + 4 + half, e3 = j + 6 + half;
      unsigned o0 = (unsigned)sOff[slot][e0] + cb2;
      unsigned o1 = (unsigned)sOff[slot][e1] + cb2;
      unsigned o2 = (unsigned)sOff[slot][e2] + cb2;
      unsigned o3 = (unsigned)sOff[slot][e3] + cb2;
      float w0 = sW[slot][e0 * 4 + h], w1 = sW[slot][e1 * 4 + h];
      float w2 = sW[slot][e2 * 4 + h], w3 = sW[slot][e3 * 4 + h];
      uint2 r0v = *(const uint2*)(hb + o0);
      uint2 r1v = *(const uint2*)(hb + o1);
      uint2 r2v = *(const uint2*)(hb + o2);
      uint2 r3v = *(const uint2*)(hb + o3);
      float2 f0l = __half22float2(*(const __half2*)&r0v.x);
      float2 f0h = __half22float2(*(const __half2*)&r0v.y);
      float2 f1l = __half22float2(*(const __half2*)&r1v.x);
      float2 f1h = __half22float2(*(const __half2*)&r1v.y);
      float2 f2l = __half22float2(*(const __half2*)&r2v.x);
      float2 f2h = __half22float2(*(const __half2*)&r2v.y);
      float2 f3l = __half22float2(*(const __half2*)&r3v.x);
      float2 f3h = __half22float2(*(const __half2*)&r3v.y);
      a0 = fmaf(w0, f0l.x, a0); a1 = fmaf(w0, f0l.y, a1);
      a2 = fmaf(w0, f0h.x, a2); a3 = fmaf(w0, f0h.y, a3);
      a0 = fmaf(w1, f1l.x, a0); a1 = fmaf(w1, f1l.y, a1);
      a2 = fmaf(w1, f1h.x, a2); a3 = fmaf(w1, f1h.y, a3);
      a0 = fmaf(w2, f2l.x, a0); a1 = fmaf(w2, f2l.y, a1);
      a2 = fmaf(w2, f2h.x, a2); a3 = fmaf(w2, f2h.y, a3);
      a0 = fmaf(w3, f3l.x, a0); a1 = fmaf(w3, f3l.y, a1);
      a2 = fmaf(w3, f3h.x, a2); a3 = fmaf(w3, f3h.y, a3);
    }
    for (; j + 2 <= degS; j += 2) {
      int e = j + half;
      unsigned o = (unsigned)sOff[slot][e] + cb2;
      float w = sW[slot][e * 4 + h];
      uint2 rv = *(const uint2*)(hb + o);
      float2 fl = __half22float2(*(const __half2*)&rv.x);
      float2 fh = __half22float2(*(const __half2*)&rv.y);
      a0 = fmaf(w, fl.x, a0); a1 = fmaf(w, fl.y, a1);
      a2 = fmaf(w, fh.x, a2); a3 = fmaf(w, fh.y, a3);
    }
    if ((degS & 1) && half == 0) {
      int e = degS - 1;
      unsigned o = (unsigned)sOff[slot][e] + cb2;
      float w = sW[slot][e * 4 + h];
      uint2 rv = *(const uint2*)(hb + o);
      float2 fl = __half22float2(*(const __half2*)&rv.x);
      float2 fh = __half22float2(*(const __half2*)&rv.y);
      a0 = fmaf(w, fl.x, a0); a1 = fmaf(w, fl.y, a1);
      a2 = fmaf(w, fh.x, a2); a3 = fmaf(w, fh.y, a3);
    }
    a0 += __shfl_xor(a0, 32);
    a1 += __shfl_xor(a1, 32);
    a2 += __shfl_xor(a2, 32);
    a3 += __shfl_xor(a3, 32);

    float den = (h == 0) ? den0 : (h == 1) ? den1 : (h == 2) ? den2 : den3;
    if (deg > KCAP) {  // cold fallback (serial, never triggers at deg~17)
      float adh = alD[(size_t)v * 4 + h];
      if (half == 0) {
        for (int e = rs + KCAP; e < re; ++e) {
          int s = csr_src[e];
          float u = expw(lrelu02(alS[(size_t)s * 4 + h] + adh));
          den += u;
          uint2 rv = *(const uint2*)(hb + ((unsigned)(s << RSH) + cb2));
          float2 fl = __half22float2(*(const __half2*)&rv.x);
          float2 fh = __half22float2(*(const __half2*)&rv.y);
          a0 = fmaf(u, fl.x, a0); a1 = fmaf(u, fl.y, a1);
          a2 = fmaf(u, fh.x, a2); a3 = fmaf(u, fh.y, a3);
        }
      } else {
        for (int e = rs + KCAP; e < re; ++e) {
          int s = csr_src[e];
          den += expw(lrelu02(alS[(size_t)s * 4 + h] + adh));
        }
      }
    }
    if (active && half == 0) {
      float inv = 1.f / (den + 1e-16f);
      float4 b4 = *(const float4*)(bias + c);
      float g0 = a0 * inv + b4.x;
      float g1 = a1 * inv + b4.y;
      float g2 = a2 * inv + b4.z;
      float g3 = a3 * inv + b4.w;
      if constexpr (BN) {
        float4 bw = *(const float4*)(bnw + c);
        float4 bb = *(const float4*)(bnb + c);
        float4 bm = *(const float4*)(bnm + c);
        float4 bv = *(const float4*)(bnv + c);
        g0 = fmaxf((g0 - bm.x) * (bw.x * rsqrtf(bv.x + 1e-5f)) + bb.x, 0.f);
        g1 = fmaxf((g1 - bm.y) * (bw.y * rsqrtf(bv.y + 1e-5f)) + bb.y, 0.f);
        g2 = fmaxf((g2 - bm.z) * (bw.z * rsqrtf(bv.z + 1e-5f)) + bb.z, 0.f);
        g3 = fmaxf((g3 - bm.w) * (bw.w * rsqrtf(bv.w + 1e-5f)) + bb.w, 0.f);
      }
      if constexpr (sizeof(OutT) == 2) {
        __half2 p0 = __floats2half2_rn(g0, g1);
        __half2 p1 = __floats2half2_rn(g2, g3);
        uint2 pk;
        pk.x = *(unsigned*)&p0;
        pk.y = *(unsigned*)&p1;
        *(uint2*)((__half*)out + (size_t)v * 128 + c) = pk;
      } else {
        *(float4*)((float*)out + (size_t)v * 128 + c) = make_float4(g0, g1, g2, g3);
      }
    }
  } else {  // H == 1, C == 32
    float ad = active ? alD[v] : 0.f;
    float den = 0.f;
    for (int k = sl; k < degS; k += 32) {
      int s = csr_src[rs + k];
      sOff[slot][k] = s << RSH;
      float u = expw(lrelu02(alS[s] + ad));
      sW[slot][k] = u;
      den += u;
    }
#pragma unroll
    for (int off = 16; off >= 1; off >>= 1) den += __shfl_xor(den, off);

    // edge-pair: lanes 0-15 even edges, 16-31 odd; 2 ch/lane (__half2)
    const int quad = sl >> 4;
    const int l4 = sl & 15;
    const int c2 = l4 * 2;
    const unsigned cb2 = (unsigned)(c2 * 2);
    float a0 = 0.f, a1 = 0.f;
    int j = 0;
    for (; j + 4 <= degS; j += 4) {
      int e0 = j + quad, e1 = j + 2 + quad;
      unsigned o0 = (unsigned)sOff[slot][e0] + cb2;
      unsigned o1 = (unsigned)sOff[slot][e1] + cb2;
      float w0 = sW[slot][e0], w1 = sW[slot][e1];
      float2 f0 = __half22float2(*(const __half2*)(hb + o0));
      float2 f1 = __half22float2(*(const __half2*)(hb + o1));
      a0 = fmaf(w0, f0.x, a0); a1 = fmaf(w0, f0.y, a1);
      a0 = fmaf(w1, f1.x, a0); a1 = fmaf(w1, f1.y, a1);
    }
    for (; j + 2 <= degS; j += 2) {
      int e = j + quad;
      unsigned o = (unsigned)sOff[slot][e] + cb2;
      float w = sW[slot][e];
      float2 f = __half22float2(*(const __half2*)(hb + o));
      a0 = fmaf(w, f.x, a0); a1 = fmaf(w, f.y, a1);
    }
    if ((degS & 1) && quad == 0) {
      int e = degS - 1;
      unsigned o = (unsigned)sOff[slot][e] + cb2;
      float w = sW[slot][e];
      float2 f = __half22float2(*(const __half2*)(hb + o));
      a0 = fmaf(w, f.x, a0); a1 = fmaf(w, f.y, a1);
    }
    a0 += __shfl_xor(a0, 16);
    a1 += __shfl_xor(a1, 16);

    if (deg > KCAP) {
      if (quad == 0) {
        for (int e = rs + KCAP; e < re; ++e) {
          int s = csr_src[e];
          float u = expw(lrelu02(alS[s] + ad));
          den += u;
          float2 f = __half22float2(*(const __half2*)(hb + ((unsigned)(s << RSH) + cb2)));
          a0 = fmaf(u, f.x, a0); a1 = fmaf(u, f.y, a1);
        }
      } else {
        for (int e = rs + KCAP; e < re; ++e)
          den += expw(lrelu02(alS[csr_src[e]] + ad));
      }
    }
    if (active && quad == 0) {
      float inv = 1.f / (den + 1e-16f);
      float2 b2v = *(const float2*)(bias + c2);
      ((float2*)((float*)out + (size_t)v * 32))[l4] =
          make_float2(a0 * inv + b2v.x, a1 * inv + b2v.y);
    }
  }
}

// ---------------------------------------------------------------------------
extern "C" void kernel_launch(void* const* d_in, const int* in_sizes, int n_in,
                              void* d_out, int out_size, void* d_ws, size_t ws_size,
                              hipStream_t stream) {
  const float* x = (const float*)d_in[0];
  const void* ei = d_in[1];
  const float* w1 = (const float*)d_in[2];
  const float* as1 = (const float*)d_in[3];
  const float* ad1 = (const float*)d_in[4];
  const float* b1 = (const float*)d_in[5];
  const float* bn1w = (const float*)d_in[6];
  const float* bn1b = (const float*)d_in[7];
  const float* bn1m = (const float*)d_in[8];
  const float* bn1v = (const float*)d_in[9];
  const float* w2 = (const float*)d_in[10];
  const float* as2 = (const float*)d_in[11];
  const float* ad2 = (const float*)d_in[12];
  const float* b2 = (const float*)d_in[13];
  const float* bn2w = (const float*)d_in[14];
  const float* bn2b = (const float*)d_in[15];
  const float* bn2m = (const float*)d_in[16];
  const float* bn2v = (const float*)d_in[17];
  const float* w3 = (const float*)d_in[18];
  const float* as3 = (const float*)d_in[19];
  const float* ad3 = (const float*)d_in[20];
  const float* b3 = (const float*)d_in[21];

  const int N = in_sizes[0] / 128;
  const int E = in_sizes[1] / 2;
  const int nbk = (N + 127) / 128;
  const int chunk = (E + NBCHUNK - 1) / NBCHUNK;

  // workspace layout (256B aligned slices)
  char* base = (char*)d_ws;
  size_t off = 0;
  auto alloc = [&](size_t bytes) {
    void* p = base + off;
    off = (off + bytes + 255) & ~(size_t)255;
    return p;
  };
  int* cnt = (int*)alloc(4);
  int* counts = (int*)alloc((size_t)NBCHUNK * nbk * 4);
  int* T = (int*)alloc((size_t)nbk * 4);
  int* EB = (int*)alloc((size_t)(nbk + 1) * 4);
  unsigned* binned = (unsigned*)alloc((size_t)E * 4);
  int* row_ptr = (int*)alloc((size_t)(N + 1) * 4);
  int* csr_src = (int*)alloc((size_t)(E + N) * 4);
  _Float16* Wt1 = (_Float16*)alloc((size_t)128 * 128 * 2);
  _Float16* Wt2 = (_Float16*)alloc((size_t)128 * 128 * 2);
  _Float16* Wt3 = (_Float16*)alloc((size_t)32 * 128 * 2);
  __half* hbuf = (__half*)alloc((size_t)N * 128 * 2);
  __half* gbuf = (__half*)alloc((size_t)N * 128 * 2);
  float* alS = (float*)alloc((size_t)N * 4 * 4);
  float* alD = (float*)alloc((size_t)N * 4 * 4);
  (void)ws_size;

  // ---- CSR build: 4 launches, zero global atomics on hot paths ----
  bcount_kernel<<<NBCHUNK + 16, 256, 0, stream>>>(ei, E, counts, nbk, chunk,
                                                  w1, w2, w3, Wt1, Wt2, Wt3, cnt);
  bscanT_kernel<<<nbk, NBCHUNK, 0, stream>>>(counts, T, EB, cnt, nbk);
  bemit_kernel<<<NBCHUNK, 256, 0, stream>>>(ei, E, counts, EB, nbk, chunk, binned);
  bscatter2_kernel<<<nbk, 256, 0, stream>>>(binned, EB, row_ptr, csr_src, N, E);

  const int rowBlocks = (N + 63) / 64;

  // ---- layer 1 ----
  mfma_gemm_al_kernel<128, 4, float><<<rowBlocks, 256, 0, stream>>>(
      x, Wt1, as1, ad1, hbuf, alS, alD, N);
  agg_kernel<4, true, __half><<<(N + 3) / 4, 256, 0, stream>>>(
      row_ptr, csr_src, alS, alD, hbuf, b1, bn1w, bn1b, bn1m, bn1v, gbuf, N);
  // ---- layer 2 ----
  mfma_gemm_al_kernel<128, 4, __half><<<rowBlocks, 256, 0, stream>>>(
      gbuf, Wt2, as2, ad2, hbuf, alS, alD, N);
  agg_kernel<4, true, __half><<<(N + 3) / 4, 256, 0, stream>>>(
      row_ptr, csr_src, alS, alD, hbuf, b2, bn2w, bn2b, bn2m, bn2v, gbuf, N);
  // ---- layer 3 ----
  mfma_gemm_al_kernel<32, 1, __half><<<rowBlocks, 256, 0, stream>>>(
      gbuf, Wt3, as3, ad3, hbuf, alS, alD, N);
  agg_kernel<1, false, float><<<(N + 7) / 8, 256, 0, stream>>>(
      row_ptr, csr_src, alS, alD, hbuf, b3, nullptr, nullptr, nullptr, nullptr,
      (float*)d_out, N);
}

// Round 14
// 187.588 us; speedup vs baseline: 2.0135x; 1.1172x over previous
//
#include <hip/hip_runtime.h>
#include <hip/hip_fp16.h>
#include <cstdint>

// ---------------------------------------------------------------------------
// EpilepsyGNN: 3-layer GAT (4 heads x 32 -> 4x32 -> 1x32), BN(eval)+ReLU
// R12/R13 lessons: device-scope sync (grid.sync ~50us, threadfence ~17us
// aggregate) is expensive on 8-XCD MI355X; kernel boundaries are cheap.
// Build = 5 fence-free launches: bcount(+wcvt in 16 spare blocks), bscanT,
// bscanE, bemit, bscatter2. Zero global atomics.
// GEMM: MFMA f16 (v_mfma_f32_16x16x32_f16), LDS-staged, f32 accum, al logits
// in epilogue. agg: fabric-pinned (R10/R11 double-null at 41us), no-max
// softmax, exp hoisted to staging, edge-pair f16 gathers.
// ---------------------------------------------------------------------------

#define NBCHUNK 128   // edge chunks for bucket counting/emission
#define MAXBK 512     // max buckets of 128 nodes (N <= 65536; packing needs it)

typedef _Float16 f16x8 __attribute__((ext_vector_type(8)));
typedef float f32x4 __attribute__((ext_vector_type(4)));

__device__ __forceinline__ float lrelu02(float x) {
  return x > 0.f ? x : 0.2f * x;
}

__device__ __forceinline__ float expw(float x) {
  return __expf(fminf(x, 80.f));   // clamp is a no-op for this data; inf guard
}

// thread-0 sniff: int64 (little-endian) edge_index has all-odd words == 0
__device__ __forceinline__ int detect64(const unsigned* ei) {
  int is64 = 1;
  for (int i = 1; i < 128; i += 2)
    if (ei[i] != 0u) { is64 = 0; break; }
  return is64;
}

// --- phase 1: per-chunk LDS histogram; 16 spare blocks do W->Wt f16 ---------
__global__ __launch_bounds__(256) void bcount_kernel(
    const void* __restrict__ ei, int E, int* __restrict__ counts,
    int nbk, int chunk,
    const float* __restrict__ W1, const float* __restrict__ W2,
    const float* __restrict__ W3,
    _Float16* __restrict__ Wt1, _Float16* __restrict__ Wt2,
    _Float16* __restrict__ Wt3) {
  const int b = blockIdx.x;
  const int t = threadIdx.x;
  if (b < NBCHUNK) {
    __shared__ int hist[MAXBK];
    __shared__ int sIs64;
    for (int i = t; i < nbk; i += 256) hist[i] = 0;
    if (t == 0) sIs64 = detect64((const unsigned*)ei);
    __syncthreads();
    int lo = b * chunk;
    int hi = lo + chunk; if (hi > E) hi = E;
    const bool is64 = sIs64 != 0;
    for (int e = lo + t; e < hi; e += 256) {
      int d = is64 ? (int)((const long long*)ei)[(size_t)E + e] : ((const int*)ei)[E + e];
      atomicAdd(&hist[d >> 7], 1);
    }
    __syncthreads();
    for (int i = t; i < nbk; i += 256)
      counts[(size_t)b * nbk + i] = hist[i];
  } else {
    // W -> Wt f16 transposes over the 16 spare blocks (36864 elements)
    for (int idx = (b - NBCHUNK) * 256 + t; idx < 36864; idx += 16 * 256) {
      if (idx < 16384) {
        int k = idx >> 7, c = idx & 127;
        Wt1[(size_t)c * 128 + k] = (_Float16)W1[idx];
      } else if (idx < 32768) {
        int i = idx - 16384;
        int k = i >> 7, c = i & 127;
        Wt2[(size_t)c * 128 + k] = (_Float16)W2[i];
      } else {
        int i = idx - 32768;
        int k = i >> 5, c = i & 31;
        Wt3[(size_t)c * 128 + k] = (_Float16)W3[i];
      }
    }
  }
}

// --- phase 2a: per-bucket exclusive scan over chunks; totals -> T -----------
__global__ void bscanT_kernel(int* __restrict__ counts, int* __restrict__ T, int nbk) {
  int b = blockIdx.x;
  int t = threadIdx.x;           // NBCHUNK = 128 threads
  int lane = t & 63;
  int v = counts[(size_t)t * nbk + b];
  int inc = v;
#pragma unroll
  for (int off = 1; off < 64; off <<= 1) {
    int u = __shfl_up(inc, off);
    if (lane >= off) inc += u;
  }
  __shared__ int w0;
  if (t == 63) w0 = inc;
  __syncthreads();
  int wb = (t >= 64) ? w0 : 0;
  counts[(size_t)t * nbk + b] = wb + inc - v;   // chunk-exclusive, bucket-local
  if (t == 127) T[b] = wb + inc;                // bucket edge total
}

// --- phase 2b: single-wave exclusive scan of bucket totals -> EB ------------
__global__ void bscanE_kernel(const int* __restrict__ T, int* __restrict__ EB, int nbk) {
  int lane = threadIdx.x;  // 64 threads
  int carry = 0;
  for (int start = 0; start < nbk; start += 64) {
    int i = start + lane;
    int v = (i < nbk) ? T[i] : 0;
    int inc = v;
#pragma unroll
    for (int off = 1; off < 64; off <<= 1) {
      int u = __shfl_up(inc, off);
      if (lane >= off) inc += u;
    }
    if (i < nbk) EB[i] = inc - v + carry;
    carry += __shfl(inc, 63);
  }
  if (lane == 0) EB[nbk] = carry;
}

// --- phase 3: emit packed (dloc<<16 | src) bucket-contiguously --------------
__global__ __launch_bounds__(256) void bemit_kernel(const void* __restrict__ ei, int E,
                                                    const int* __restrict__ counts,
                                                    const int* __restrict__ EB,
                                                    int nbk, int chunk,
                                                    unsigned* __restrict__ binned) {
  __shared__ int cur[MAXBK];
  __shared__ int sIs64;
  for (int i = threadIdx.x; i < nbk; i += 256)
    cur[i] = counts[(size_t)blockIdx.x * nbk + i] + EB[i];
  if (threadIdx.x == 0) sIs64 = detect64((const unsigned*)ei);
  __syncthreads();
  int lo = blockIdx.x * chunk;
  int hi = lo + chunk; if (hi > E) hi = E;
  const bool is64 = sIs64 != 0;
  for (int e = lo + threadIdx.x; e < hi; e += 256) {
    int s, d;
    if (is64) {
      const long long* p = (const long long*)ei;
      s = (int)p[e];
      d = (int)p[(size_t)E + e];
    } else {
      const int* p = (const int*)ei;
      s = p[e];
      d = p[E + e];
    }
    int pos = atomicAdd(&cur[d >> 7], 1);   // LDS atomic: cheap
    binned[pos] = ((unsigned)(d & 127) << 16) | (unsigned)s;   // N <= 65536
  }
}

// --- phase 4: per-bucket histogram -> row_ptr + self-loops + scatter --------
__global__ __launch_bounds__(256) void bscatter2_kernel(const unsigned* __restrict__ binned,
                                                        const int* __restrict__ EB,
                                                        int* __restrict__ row_ptr,
                                                        int* __restrict__ csr_src,
                                                        int n, int E) {
  __shared__ int hist[128];
  __shared__ int cur[128];
  __shared__ int w0s;
  const int b = blockIdx.x;
  const int t = threadIdx.x;
  const int bb = b << 7;
  if (t < 128) hist[t] = 0;
  __syncthreads();
  const int lo = EB[b], hi = EB[b + 1];
  for (int i = lo + t; i < hi; i += 256)
    atomicAdd(&hist[binned[i] >> 16], 1);
  __syncthreads();
  int lane = t & 63;
  int v = (t < 128) ? hist[t] : 0;
  int inc = v;
#pragma unroll
  for (int off = 1; off < 64; off <<= 1) {
    int u = __shfl_up(inc, off);
    if (lane >= off) inc += u;
  }
  if (t == 63) w0s = inc;
  __syncthreads();
  int exc = ((t >= 64 && t < 128) ? w0s : 0) + inc - v;
  if (t < 128 && bb + t < n) {
    int rp = EB[b] + bb + t + exc;   // edges-before-node + self-loops-before
    row_ptr[bb + t] = rp;
    csr_src[rp] = bb + t;            // self loop at slot 0
    cur[t] = rp + 1;
  }
  if (b == 0 && t == 0) row_ptr[n] = E + n;
  __syncthreads();
  for (int i = lo + t; i < hi; i += 256) {
    unsigned pv = binned[i];
    int pos = atomicAdd(&cur[pv >> 16], 1);
    csr_src[pos] = (int)(pv & 0xFFFFu);
  }
}

// --- MFMA GEMM + al epilogue: A[n,128]@W[128,OUTC] -> H(f16), alS/alD(f32) --
template <int OUTC, int H, typename AT>
__global__ __launch_bounds__(256) void mfma_gemm_al_kernel(
    const AT* __restrict__ A, const _Float16* __restrict__ Wt,
    const float* __restrict__ a_src, const float* __restrict__ a_dst,
    __half* __restrict__ Hout, float* __restrict__ alS, float* __restrict__ alD,
    int n) {
  constexpr int NT = OUTC / 16;    // col tiles per wave (8 or 2)
  constexpr int APH = 136;         // LDS row stride in halves (16B-aligned rows)

  __shared__ __align__(16) _Float16 A_lds[64 * APH];
  __shared__ __align__(16) _Float16 W_lds[OUTC * APH];

  const int t = threadIdx.x;
  const int r0 = blockIdx.x * 64;

  if constexpr (sizeof(AT) == 4) {
#pragma unroll
    for (int i = 0; i < 8; ++i) {
      int slot = t + i * 256;
      int r = slot >> 5, q = slot & 31;
      float4 v = make_float4(0.f, 0.f, 0.f, 0.f);
      if (r0 + r < n) v = *(const float4*)((const float*)A + (size_t)(r0 + r) * 128 + q * 4);
      __half2 p0 = __floats2half2_rn(v.x, v.y);
      __half2 p1 = __floats2half2_rn(v.z, v.w);
      uint2 pk;
      pk.x = *(unsigned*)&p0;
      pk.y = *(unsigned*)&p1;
      *(uint2*)&A_lds[r * APH + q * 4] = pk;
    }
  } else {
#pragma unroll
    for (int i = 0; i < 4; ++i) {
      int slot = t + i * 256;
      int r = slot >> 4, q = slot & 15;
      uint4 raw = make_uint4(0u, 0u, 0u, 0u);
      if (r0 + r < n) raw = *(const uint4*)((const __half*)A + (size_t)(r0 + r) * 128 + q * 8);
      *(uint4*)&A_lds[r * APH + q * 8] = raw;
    }
  }
#pragma unroll
  for (int i = 0; i < OUTC / 16; ++i) {
    int slot = t + i * 256;
    int c = slot >> 4, q = slot & 15;
    uint4 raw = *(const uint4*)(Wt + (size_t)c * 128 + q * 8);
    *(uint4*)&W_lds[c * APH + q * 8] = raw;
  }
  __syncthreads();

  const int w = t >> 6;
  const int lane = t & 63;
  const int lrow = lane & 15;
  const int lk = lane >> 4;

  f32x4 acc[NT];
#pragma unroll
  for (int i = 0; i < NT; ++i) acc[i] = (f32x4){0.f, 0.f, 0.f, 0.f};

#pragma unroll
  for (int kc = 0; kc < 4; ++kc) {
    f16x8 a = *(const f16x8*)&A_lds[(w * 16 + lrow) * APH + kc * 32 + lk * 8];
#pragma unroll
    for (int ct = 0; ct < NT; ++ct) {
      f16x8 b = *(const f16x8*)&W_lds[(ct * 16 + lrow) * APH + kc * 32 + lk * 8];
      acc[ct] = __builtin_amdgcn_mfma_f32_16x16x32_f16(a, b, acc[ct], 0, 0, 0);
    }
  }

  const int rbase = r0 + w * 16 + lk * 4;
#pragma unroll
  for (int ct = 0; ct < NT; ++ct) {
#pragma unroll
    for (int j = 0; j < 4; ++j) {
      int r = rbase + j;
      if (r < n) Hout[(size_t)r * OUTC + ct * 16 + lrow] = __float2half(acc[ct][j]);
    }
  }

#pragma unroll
  for (int h = 0; h < H; ++h) {
    float as0 = a_src[h * 32 + lrow], as1 = a_src[h * 32 + 16 + lrow];
    float ad0 = a_dst[h * 32 + lrow], ad1 = a_dst[h * 32 + 16 + lrow];
#pragma unroll
    for (int j = 0; j < 4; ++j) {
      float ps = acc[2 * h][j] * as0 + acc[2 * h + 1][j] * as1;
      float pd = acc[2 * h][j] * ad0 + acc[2 * h + 1][j] * ad1;
#pragma unroll
      for (int off = 1; off < 16; off <<= 1) {
        ps += __shfl_xor(ps, off);
        pd += __shfl_xor(pd, off);
      }
      if (lrow == 0) {
        int r = rbase + j;
        if (r < n) {
          alS[(size_t)r * H + h] = ps;
          alD[(size_t)r * H + h] = pd;
        }
      }
    }
  }
}

// --- agg: staged exp weights, edge-PAIR f16 gathers, shfl combine -----------
template <int H, bool BN, typename OutT>
__global__ __launch_bounds__(256) void agg_kernel(
    const int* __restrict__ row_ptr, const int* __restrict__ csr_src,
    const float* __restrict__ alS, const float* __restrict__ alD,
    const __half* __restrict__ hfeat, const float* __restrict__ bias,
    const float* __restrict__ bnw, const float* __restrict__ bnb,
    const float* __restrict__ bnm, const float* __restrict__ bnv,
    OutT* __restrict__ out, int n) {
  constexpr int LPN = (H == 4) ? 64 : 32;     // lanes per node
  constexpr int NPB = 256 / LPN;              // node slots per block
  constexpr int KCAP = 96;                    // staged-edge capacity
  constexpr int RSH = (H == 4) ? 8 : 6;       // log2(row bytes): 256B / 64B

  __shared__ __align__(16) float sW[NPB][KCAP * H];
  __shared__ int sOff[NPB][KCAP];

  const int slot = threadIdx.x / LPN;
  const int sl = threadIdx.x % LPN;
  const int v = blockIdx.x * NPB + slot;
  const bool active = v < n;
  const char* hb = (const char*)hfeat;

  int rs = 0, re = 0;
  if (active) { rs = row_ptr[v]; re = row_ptr[v + 1]; }
  const int deg = re - rs;
  const int degS = deg < KCAP ? deg : KCAP;

  if constexpr (H == 4) {
    float4 ad4 = make_float4(0.f, 0.f, 0.f, 0.f);
    if (active) ad4 = *(const float4*)(alD + (size_t)v * 4);
    float den0 = 0.f, den1 = 0.f, den2 = 0.f, den3 = 0.f;
    for (int k = sl; k < degS; k += 64) {
      int s = csr_src[rs + k];
      sOff[slot][k] = s << RSH;
      float4 a4 = *(const float4*)(alS + (size_t)s * 4);
      float u0 = expw(lrelu02(a4.x + ad4.x));
      float u1 = expw(lrelu02(a4.y + ad4.y));
      float u2 = expw(lrelu02(a4.z + ad4.z));
      float u3 = expw(lrelu02(a4.w + ad4.w));
      ((float4*)&sW[slot][0])[k] = make_float4(u0, u1, u2, u3);
      den0 += u0; den1 += u1; den2 += u2; den3 += u3;
    }
#pragma unroll
    for (int off = 32; off >= 1; off >>= 1) {
      den0 += __shfl_xor(den0, off);
      den1 += __shfl_xor(den1, off);
      den2 += __shfl_xor(den2, off);
      den3 += __shfl_xor(den3, off);
    }

    // edge-pair: lanes 0-31 even edges, lanes 32-63 odd edges; 4 ch/lane
    const int half = sl >> 5;
    const int l5 = sl & 31;
    const int c = l5 * 4;
    const int h = l5 >> 3;
    const unsigned cb2 = (unsigned)(c * 2);
    float a0 = 0.f, a1 = 0.f, a2 = 0.f, a3 = 0.f;
    int j = 0;
    for (; j + 8 <= degS; j += 8) {
      int e0 = j + half, e1 = j + 2 + half, e2 = j + 4 + half, e3 = j + 6 + half;
      unsigned o0 = (unsigned)sOff[slot][e0] + cb2;
      unsigned o1 = (unsigned)sOff[slot][e1] + cb2;
      unsigned o2 = (unsigned)sOff[slot][e2] + cb2;
      unsigned o3 = (unsigned)sOff[slot][e3] + cb2;
      float w0 = sW[slot][e0 * 4 + h], w1 = sW[slot][e1 * 4 + h];
      float w2 = sW[slot][e2 * 4 + h], w3 = sW[slot][e3 * 4 + h];
      uint2 r0v = *(const uint2*)(hb + o0);
      uint2 r1v = *(const uint2*)(hb + o1);
      uint2 r2v = *(const uint2*)(hb + o2);
      uint2 r3v = *(const uint2*)(hb + o3);
      float2 f0l = __half22float2(*(const __half2*)&r0v.x);
      float2 f0h = __half22float2(*(const __half2*)&r0v.y);
      float2 f1l = __half22float2(*(const __half2*)&r1v.x);
      float2 f1h = __half22float2(*(const __half2*)&r1v.y);
      float2 f2l = __half22float2(*(const __half2*)&r2v.x);
      float2 f2h = __half22float2(*(const __half2*)&r2v.y);
      float2 f3l = __half22float2(*(const __half2*)&r3v.x);
      float2 f3h = __half22float2(*(const __half2*)&r3v.y);
      a0 = fmaf(w0, f0l.x, a0); a1 = fmaf(w0, f0l.y, a1);
      a2 = fmaf(w0, f0h.x, a2); a3 = fmaf(w0, f0h.y, a3);
      a0 = fmaf(w1, f1l.x, a0); a1 = fmaf(w1, f1l.y, a1);
      a2 = fmaf(w1, f1h.x, a2); a3 = fmaf(w1, f1h.y, a3);
      a0 = fmaf(w2, f2l.x, a0); a1 = fmaf(w2, f2l.y, a1);
      a2 = fmaf(w2, f2h.x, a2); a3 = fmaf(w2, f2h.y, a3);
      a0 = fmaf(w3, f3l.x, a0); a1 = fmaf(w3, f3l.y, a1);
      a2 = fmaf(w3, f3h.x, a2); a3 = fmaf(w3, f3h.y, a3);
    }
    for (; j + 2 <= degS; j += 2) {
      int e = j + half;
      unsigned o = (unsigned)sOff[slot][e] + cb2;
      float w = sW[slot][e * 4 + h];
      uint2 rv = *(const uint2*)(hb + o);
      float2 fl = __half22float2(*(const __half2*)&rv.x);
      float2 fh = __half22float2(*(const __half2*)&rv.y);
      a0 = fmaf(w, fl.x, a0); a1 = fmaf(w, fl.y, a1);
      a2 = fmaf(w, fh.x, a2); a3 = fmaf(w, fh.y, a3);
    }
    if ((degS & 1) && half == 0) {
      int e = degS - 1;
      unsigned o = (unsigned)sOff[slot][e] + cb2;
      float w = sW[slot][e * 4 + h];
      uint2 rv = *(const uint2*)(hb + o);
      float2 fl = __half22float2(*(const __half2*)&rv.x);
      float2 fh = __half22float2(*(const __half2*)&rv.y);
      a0 = fmaf(w, fl.x, a0); a1 = fmaf(w, fl.y, a1);
      a2 = fmaf(w, fh.x, a2); a3 = fmaf(w, fh.y, a3);
    }
    a0 += __shfl_xor(a0, 32);
    a1 += __shfl_xor(a1, 32);
    a2 += __shfl_xor(a2, 32);
    a3 += __shfl_xor(a3, 32);

    float den = (h == 0) ? den0 : (h == 1) ? den1 : (h == 2) ? den2 : den3;
    if (deg > KCAP) {  // cold fallback (serial, never triggers at deg~17)
      float adh = alD[(size_t)v * 4 + h];
      if (half == 0) {
        for (int e = rs + KCAP; e < re; ++e) {
          int s = csr_src[e];
          float u = expw(lrelu02(alS[(size_t)s * 4 + h] + adh));
          den += u;
          uint2 rv = *(const uint2*)(hb + ((unsigned)(s << RSH) + cb2));
          float2 fl = __half22float2(*(const __half2*)&rv.x);
          float2 fh = __half22float2(*(const __half2*)&rv.y);
          a0 = fmaf(u, fl.x, a0); a1 = fmaf(u, fl.y, a1);
          a2 = fmaf(u, fh.x, a2); a3 = fmaf(u, fh.y, a3);
        }
      } else {
        for (int e = rs + KCAP; e < re; ++e) {
          int s = csr_src[e];
          den += expw(lrelu02(alS[(size_t)s * 4 + h] + adh));
        }
      }
    }
    if (active && half == 0) {
      float inv = 1.f / (den + 1e-16f);
      float4 b4 = *(const float4*)(bias + c);
      float g0 = a0 * inv + b4.x;
      float g1 = a1 * inv + b4.y;
      float g2 = a2 * inv + b4.z;
      float g3 = a3 * inv + b4.w;
      if constexpr (BN) {
        float4 bw = *(const float4*)(bnw + c);
        float4 bb = *(const float4*)(bnb + c);
        float4 bm = *(const float4*)(bnm + c);
        float4 bv = *(const float4*)(bnv + c);
        g0 = fmaxf((g0 - bm.x) * (bw.x * rsqrtf(bv.x + 1e-5f)) + bb.x, 0.f);
        g1 = fmaxf((g1 - bm.y) * (bw.y * rsqrtf(bv.y + 1e-5f)) + bb.y, 0.f);
        g2 = fmaxf((g2 - bm.z) * (bw.z * rsqrtf(bv.z + 1e-5f)) + bb.z, 0.f);
        g3 = fmaxf((g3 - bm.w) * (bw.w * rsqrtf(bv.w + 1e-5f)) + bb.w, 0.f);
      }
      if constexpr (sizeof(OutT) == 2) {
        __half2 p0 = __floats2half2_rn(g0, g1);
        __half2 p1 = __floats2half2_rn(g2, g3);
        uint2 pk;
        pk.x = *(unsigned*)&p0;
        pk.y = *(unsigned*)&p1;
        *(uint2*)((__half*)out + (size_t)v * 128 + c) = pk;
      } else {
        *(float4*)((float*)out + (size_t)v * 128 + c) = make_float4(g0, g1, g2, g3);
      }
    }
  } else {  // H == 1, C == 32
    float ad = active ? alD[v] : 0.f;
    float den = 0.f;
    for (int k = sl; k < degS; k += 32) {
      int s = csr_src[rs + k];
      sOff[slot][k] = s << RSH;
      float u = expw(lrelu02(alS[s] + ad));
      sW[slot][k] = u;
      den += u;
    }
#pragma unroll
    for (int off = 16; off >= 1; off >>= 1) den += __shfl_xor(den, off);

    // edge-pair: lanes 0-15 even edges, 16-31 odd; 2 ch/lane (__half2)
    const int quad = sl >> 4;
    const int l4 = sl & 15;
    const int c2 = l4 * 2;
    const unsigned cb2 = (unsigned)(c2 * 2);
    float a0 = 0.f, a1 = 0.f;
    int j = 0;
    for (; j + 4 <= degS; j += 4) {
      int e0 = j + quad, e1 = j + 2 + quad;
      unsigned o0 = (unsigned)sOff[slot][e0] + cb2;
      unsigned o1 = (unsigned)sOff[slot][e1] + cb2;
      float w0 = sW[slot][e0], w1 = sW[slot][e1];
      float2 f0 = __half22float2(*(const __half2*)(hb + o0));
      float2 f1 = __half22float2(*(const __half2*)(hb + o1));
      a0 = fmaf(w0, f0.x, a0); a1 = fmaf(w0, f0.y, a1);
      a0 = fmaf(w1, f1.x, a0); a1 = fmaf(w1, f1.y, a1);
    }
    for (; j + 2 <= degS; j += 2) {
      int e = j + quad;
      unsigned o = (unsigned)sOff[slot][e] + cb2;
      float w = sW[slot][e];
      float2 f = __half22float2(*(const __half2*)(hb + o));
      a0 = fmaf(w, f.x, a0); a1 = fmaf(w, f.y, a1);
    }
    if ((degS & 1) && quad == 0) {
      int e = degS - 1;
      unsigned o = (unsigned)sOff[slot][e] + cb2;
      float w = sW[slot][e];
      float2 f = __half22float2(*(const __half2*)(hb + o));
      a0 = fmaf(w, f.x, a0); a1 = fmaf(w, f.y, a1);
    }
    a0 += __shfl_xor(a0, 16);
    a1 += __shfl_xor(a1, 16);

    if (deg > KCAP) {
      if (quad == 0) {
        for (int e = rs + KCAP; e < re; ++e) {
          int s = csr_src[e];
          float u = expw(lrelu02(alS[s] + ad));
          den += u;
          float2 f = __half22float2(*(const __half2*)(hb + ((unsigned)(s << RSH) + cb2)));
          a0 = fmaf(u, f.x, a0); a1 = fmaf(u, f.y, a1);
        }
      } else {
        for (int e = rs + KCAP; e < re; ++e)
          den += expw(lrelu02(alS[csr_src[e]] + ad));
      }
    }
    if (active && quad == 0) {
      float inv = 1.f / (den + 1e-16f);
      float2 b2v = *(const float2*)(bias + c2);
      ((float2*)((float*)out + (size_t)v * 32))[l4] =
          make_float2(a0 * inv + b2v.x, a1 * inv + b2v.y);
    }
  }
}

// ---------------------------------------------------------------------------
extern "C" void kernel_launch(void* const* d_in, const int* in_sizes, int n_in,
                              void* d_out, int out_size, void* d_ws, size_t ws_size,
                              hipStream_t stream) {
  const float* x = (const float*)d_in[0];
  const void* ei = d_in[1];
  const float* w1 = (const float*)d_in[2];
  const float* as1 = (const float*)d_in[3];
  const float* ad1 = (const float*)d_in[4];
  const float* b1 = (const float*)d_in[5];
  const float* bn1w = (const float*)d_in[6];
  const float* bn1b = (const float*)d_in[7];
  const float* bn1m = (const float*)d_in[8];
  const float* bn1v = (const float*)d_in[9];
  const float* w2 = (const float*)d_in[10];
  const float* as2 = (const float*)d_in[11];
  const float* ad2 = (const float*)d_in[12];
  const float* b2 = (const float*)d_in[13];
  const float* bn2w = (const float*)d_in[14];
  const float* bn2b = (const float*)d_in[15];
  const float* bn2m = (const float*)d_in[16];
  const float* bn2v = (const float*)d_in[17];
  const float* w3 = (const float*)d_in[18];
  const float* as3 = (const float*)d_in[19];
  const float* ad3 = (const float*)d_in[20];
  const float* b3 = (const float*)d_in[21];

  const int N = in_sizes[0] / 128;
  const int E = in_sizes[1] / 2;
  const int nbk = (N + 127) / 128;
  const int chunk = (E + NBCHUNK - 1) / NBCHUNK;

  // workspace layout (256B aligned slices)
  char* base = (char*)d_ws;
  size_t off = 0;
  auto alloc = [&](size_t bytes) {
    void* p = base + off;
    off = (off + bytes + 255) & ~(size_t)255;
    return p;
  };
  int* counts = (int*)alloc((size_t)NBCHUNK * nbk * 4);
  int* T = (int*)alloc((size_t)nbk * 4);
  int* EB = (int*)alloc((size_t)(nbk + 1) * 4);
  unsigned* binned = (unsigned*)alloc((size_t)E * 4);
  int* row_ptr = (int*)alloc((size_t)(N + 1) * 4);
  int* csr_src = (int*)alloc((size_t)(E + N) * 4);
  _Float16* Wt1 = (_Float16*)alloc((size_t)128 * 128 * 2);
  _Float16* Wt2 = (_Float16*)alloc((size_t)128 * 128 * 2);
  _Float16* Wt3 = (_Float16*)alloc((size_t)32 * 128 * 2);
  __half* hbuf = (__half*)alloc((size_t)N * 128 * 2);
  __half* gbuf = (__half*)alloc((size_t)N * 128 * 2);
  float* alS = (float*)alloc((size_t)N * 4 * 4);
  float* alD = (float*)alloc((size_t)N * 4 * 4);
  (void)ws_size;

  // ---- CSR build: 5 fence-free launches, zero global atomics ----
  bcount_kernel<<<NBCHUNK + 16, 256, 0, stream>>>(ei, E, counts, nbk, chunk,
                                                  w1, w2, w3, Wt1, Wt2, Wt3);
  bscanT_kernel<<<nbk, NBCHUNK, 0, stream>>>(counts, T, nbk);
  bscanE_kernel<<<1, 64, 0, stream>>>(T, EB, nbk);
  bemit_kernel<<<NBCHUNK, 256, 0, stream>>>(ei, E, counts, EB, nbk, chunk, binned);
  bscatter2_kernel<<<nbk, 256, 0, stream>>>(binned, EB, row_ptr, csr_src, N, E);

  const int rowBlocks = (N + 63) / 64;

  // ---- layer 1 ----
  mfma_gemm_al_kernel<128, 4, float><<<rowBlocks, 256, 0, stream>>>(
      x, Wt1, as1, ad1, hbuf, alS, alD, N);
  agg_kernel<4, true, __half><<<(N + 3) / 4, 256, 0, stream>>>(
      row_ptr, csr_src, alS, alD, hbuf, b1, bn1w, bn1b, bn1m, bn1v, gbuf, N);
  // ---- layer 2 ----
  mfma_gemm_al_kernel<128, 4, __half><<<rowBlocks, 256, 0, stream>>>(
      gbuf, Wt2, as2, ad2, hbuf, alS, alD, N);
  agg_kernel<4, true, __half><<<(N + 3) / 4, 256, 0, stream>>>(
      row_ptr, csr_src, alS, alD, hbuf, b2, bn2w, bn2b, bn2m, bn2v, gbuf, N);
  // ---- layer 3 ----
  mfma_gemm_al_kernel<32, 1, __half><<<rowBlocks, 256, 0, stream>>>(
      gbuf, Wt3, as3, ad3, hbuf, alS, alD, N);
  agg_kernel<1, false, float><<<(N + 7) / 8, 256, 0, stream>>>(
      row_ptr, csr_src, alS, alD, hbuf, b3, nullptr, nullptr, nullptr, nullptr,
      (float*)d_out, N);
}